// Round 10
// baseline (933.272 us; speedup 1.0000x reference)
//
#include <hip/hip_runtime.h>

// Problem constants (from reference)
constexpr int B_ = 8;
constexpr int N_ = 16384;
constexpr int NG = 512;     // NUM_GROUPS
constexpr int GS = 32;      // GROUP_SIZE
constexpr int KORIG = 160;  // K_ORIGINAL = 5*GROUP_SIZE
constexpr int TPB = 1024;   // fps threads (16 waves)
constexpr int PPT = 16;     // points per thread, contiguous ownership
#define R2 0.04f
#define RADIUS 0.2f

typedef __attribute__((ext_vector_type(2))) float f32x2;
typedef __attribute__((ext_vector_type(4))) float f32x4;

__device__ __forceinline__ unsigned f32_ord(float f) {
  unsigned u = __float_as_uint(f);
  return (u & 0x80000000u) ? ~u : (u | 0x80000000u);
}

// packed f32 math: IEEE-identical per component to scalar v_add/v_mul
__device__ __forceinline__ f32x2 pk_add(f32x2 a, f32x2 b) {
  f32x2 d;
  asm("v_pk_add_f32 %0, %1, %2" : "=v"(d) : "v"(a), "v"(b));
  return d;
}
__device__ __forceinline__ f32x2 pk_mul(f32x2 a, f32x2 b) {
  f32x2 d;
  asm("v_pk_mul_f32 %0, %1, %2" : "=v"(d) : "v"(a), "v"(b));
  return d;
}

// fmax with a DPP-permuted copy; ctrl must be an immediate -> template param
template <int CTRL>
__device__ __forceinline__ float dpp_fmax(float v) {
  int o = __builtin_amdgcn_update_dpp(0, __float_as_int(v), CTRL, 0xF, 0xF, true);
  return fmaxf(v, __int_as_float(o));
}
// full 64-lane max
__device__ __forceinline__ float wave_fmax(float v) {
  v = dpp_fmax<0xB1>(v);   // quad_perm [1,0,3,2]
  v = dpp_fmax<0x4E>(v);   // quad_perm [2,3,0,1]
  v = dpp_fmax<0x141>(v);  // row_half_mirror (within 8)
  v = dpp_fmax<0x140>(v);  // row_mirror      (within 16)
  v = fmaxf(v, __int_as_float(__builtin_amdgcn_ds_swizzle(__float_as_int(v), 0x401F)));  // xor16
  v = fmaxf(v, __shfl_xor(v, 32, 64));  // xor32
  return v;
}
// max within each 16-lane group (lanes g*16..g*16+15 hold the 16 wave partials)
__device__ __forceinline__ float group16_fmax(float v) {
  v = dpp_fmax<0xB1>(v);
  v = dpp_fmax<0x4E>(v);
  v = dpp_fmax<0x141>(v);
  v = dpp_fmax<0x140>(v);
  return v;
}

// ---------------- Kernel 1: farthest point sampling ----------------
// One block per batch, 1024 threads (16 waves); thread t owns points
// [16t,16t+16) CONTIGUOUS (tie-break order = wave, lane, j = index order).
// x,y in LDS as pair-major float4 (xA,xB,yA,yB) -> 1 ds_read_b128 / 2 pts;
// z,m in registers as f32x2 pairs; distance math in v_pk_add/v_pk_mul
// (2 points per instruction, bit-exact: x+(-c) == x-c, same add order,
// contract off). Single barrier per iteration (parity publish slots).
__global__ __launch_bounds__(1024, 4) void fps_kernel(const float4* __restrict__ p4,
                                                      const int* __restrict__ lengths,
                                                      float* __restrict__ centers) {
#pragma clang fp contract(off)
  const int b = blockIdx.x;
  const int t = threadIdx.x;
  const int lane = t & 63;
  const int wid = t >> 6;
  const int len = lengths[b];
  const float4* bp = p4 + (size_t)b * N_;
  const float INF = __builtin_inff();

  __shared__ f32x4 sxy4[16 * 8 * 64];  // 128 KiB: [(wid*8+p)*64 + lane]
  __shared__ float pubf[2][16];        // per-wave max, parity dbuf
  __shared__ int pubi[2][16];          // per-wave winner index, parity dbuf

  const int base4 = wid * 512 + lane;  // + p*64

  f32x2 z2[8], m2[8];
#pragma unroll
  for (int p = 0; p < 8; ++p) {
    const int i0 = t * PPT + 2 * p;
    float4 a = bp[i0];
    float4 c = bp[i0 + 1];
    sxy4[base4 + p * 64] = (f32x4){a.x, c.x, a.y, c.y};
    z2[p] = (f32x2){a.z, c.z};
    m2[p].x = (i0 < len) ? INF : -INF;
    m2[p].y = (i0 + 1 < len) ? INF : -INF;
  }
  __syncthreads();

  float4 c0 = bp[0];  // reference scan starts at cur=0
  float cx = c0.x, cy = c0.y, cz = c0.z;
  if (t == 0) {
    size_t o = (size_t)b * NG * 3;
    centers[o] = cx; centers[o + 1] = cy; centers[o + 2] = cz;
  }

  for (int k = 0; k < NG - 1; ++k) {
    // --- mindist update: pk math, 2 points/instr, exact reference rounding ---
    const f32x2 mcx = {-cx, -cx};
    const f32x2 mcy = {-cy, -cy};
    const f32x2 mcz = {-cz, -cz};
#pragma unroll
    for (int p = 0; p < 8; ++p) {
      f32x4 q = sxy4[base4 + p * 64];   // (xA,xB,yA,yB), static-offset b128
      f32x2 xx = pk_add(q.xy, mcx);     // x - cx (as x + (-cx), exact)
      f32x2 yy = pk_add(q.zw, mcy);
      f32x2 zz = pk_add(z2[p], mcz);
      f32x2 x2 = pk_mul(xx, xx);
      f32x2 y2 = pk_mul(yy, yy);
      f32x2 s1 = pk_add(x2, y2);        // dx2 + dy2
      f32x2 zq = pk_mul(zz, zz);
      f32x2 d2 = pk_add(s1, zq);        // (dx2+dy2) + dz2 = np.sum order
      m2[p].x = fminf(m2[p].x, d2.x);
      m2[p].y = fminf(m2[p].y, d2.y);
    }
    // --- thread max: pair maxes then tree (levels kept for descent) ---
    float p0 = fmaxf(m2[0].x, m2[0].y), p1 = fmaxf(m2[1].x, m2[1].y);
    float p2 = fmaxf(m2[2].x, m2[2].y), p3 = fmaxf(m2[3].x, m2[3].y);
    float p4_ = fmaxf(m2[4].x, m2[4].y), p5 = fmaxf(m2[5].x, m2[5].y);
    float p6 = fmaxf(m2[6].x, m2[6].y), p7 = fmaxf(m2[7].x, m2[7].y);
    float r0 = fmaxf(p0, p1), r1 = fmaxf(p2, p3);
    float r2 = fmaxf(p4_, p5), r3 = fmaxf(p6, p7);
    float s0 = fmaxf(r0, r1), s1 = fmaxf(r2, r3);
    const float sm = fmaxf(s0, s1);

    // --- first-j via leftmost tree descent ---
    const bool bA = (s0 != sm);                 // 1 -> pairs 4..7
    const float rA = bA ? r2 : r0;
    const bool bB = (rA != sm);
    const float qA = bA ? (bB ? p6 : p4_) : (bB ? p2 : p0);
    const bool bC = (qA != sm);
    const int jp = ((int)bA << 2) | ((int)bB << 1) | (int)bC;
    const float xlo = bA ? (bB ? (bC ? m2[7].x : m2[6].x) : (bC ? m2[5].x : m2[4].x))
                         : (bB ? (bC ? m2[3].x : m2[2].x) : (bC ? m2[1].x : m2[0].x));
    const bool blo = (xlo != sm);               // lo half attains? else hi
    const int bj = (jp << 1) | (int)blo;

    // --- wave max + first-lane tie-break; publish (value, index) ---
    const float wmax = wave_fmax(sm);
    const unsigned long long att = __ballot(sm == wmax);
    const int wl = __ffsll(att) - 1;  // lowest lane = lowest index
    if (lane == wl) {
      pubf[k & 1][wid] = wmax;
      pubi[k & 1][wid] = t * PPT + bj;
    }
    __syncthreads();  // the only barrier in the loop

    // --- all waves: cross-wave value max, first wave wins, index broadcast ---
    const float pw = pubf[k & 1][lane & 15];
    const float kmax = group16_fmax(pw);
    const unsigned long long bal = __ballot(pw == kmax);
    const int grp = lane & 48;
    const int ww = __ffsll((bal >> grp) & 0xFFFFull) - 1;  // lowest wave wins
    const int nxt = pubi[k & 1][ww];                       // broadcast LDS read
    const int snxt = __builtin_amdgcn_readfirstlane(nxt);  // SGPR -> s_load
    const float4 c = bp[snxt];                             // wave-uniform, L2-hot
    cx = c.x; cy = c.y; cz = c.z;

    if (t == 0) {
      size_t o = ((size_t)b * NG + (k + 1)) * 3;
      centers[o] = cx; centers[o + 1] = cy; centers[o + 2] = cz;
    }
  }
}

// ---------------- Kernel 2: ball query + energy top-k + gather ----------------
// One wave per (batch, group). Ordered compaction of first 160 in-ball indices,
// then 32 rounds of min-key extraction = top_k by (energy desc, index asc).
__global__ __launch_bounds__(64) void group_kernel(const float4* __restrict__ p4,
                                                   const int* __restrict__ lengths,
                                                   const float* __restrict__ centers,
                                                   float4* __restrict__ outg) {
#pragma clang fp contract(off)
  const int gid = blockIdx.x;
  const int b = gid >> 9;
  const int lane = threadIdx.x;
  const int len = lengths[b];
  const float4* bp = p4 + (size_t)b * N_;
  const float cx = centers[(size_t)gid * 3 + 0];
  const float cy = centers[(size_t)gid * 3 + 1];
  const float cz = centers[(size_t)gid * 3 + 2];

  __shared__ int cand[KORIG];
  int M = 0;  // wave-uniform running in-ball count
  for (int cb = 0; cb < N_ && M < KORIG; cb += 256) {
#pragma unroll
    for (int q = 0; q < 4; ++q) {
      const int i = cb + q * 64 + lane;
      float4 p = bp[i];
      float dx = p.x - cx;
      float dy = p.y - cy;
      float dz = p.z - cz;
      float d2 = dx * dx + dy * dy + dz * dz;  // contract OFF
      const bool pred = (i < len) && (d2 < R2);
      unsigned long long mb = __ballot(pred);
      if (pred) {
        int pos = M + (int)__popcll(mb & ((1ull << lane) - 1ull));
        if (pos < KORIG) cand[pos] = i;  // first-160-by-index semantics
      }
      M += (int)__popcll(mb);
    }
  }
  if (M > KORIG) M = KORIG;
  __syncthreads();

  // keys: (energy desc, index asc) -> ascending u64
  const unsigned long long SENT = ~0ull;
  unsigned long long key0 = SENT, key1 = SENT, key2 = SENT;
  {
    int c0 = lane, c1 = lane + 64, c2 = lane + 128;
    if (c0 < M) { int i = cand[c0]; key0 = ((unsigned long long)(~f32_ord(bp[i].w)) << 32) | (unsigned)i; }
    if (c1 < M) { int i = cand[c1]; key1 = ((unsigned long long)(~f32_ord(bp[i].w)) << 32) | (unsigned)i; }
    if (c2 < M) { int i = cand[c2]; key2 = ((unsigned long long)(~f32_ord(bp[i].w)) << 32) | (unsigned)i; }
  }

  int mysel = -1;  // lane j holds the j-th selected index
  for (int j = 0; j < GS; ++j) {
    unsigned long long kmin = key0 < key1 ? key0 : key1;
    if (key2 < kmin) kmin = key2;
#pragma unroll
    for (int off = 32; off > 0; off >>= 1) {
      unsigned long long o = __shfl_xor(kmin, off, 64);
      if (o < kmin) kmin = o;
    }
    if (kmin == SENT) break;  // fewer than 32 candidates; rest stay -1
    if (lane == j) mysel = (int)(unsigned)kmin;
    if (key0 == kmin) key0 = SENT;
    if (key1 == kmin) key1 = SENT;
    if (key2 == kmin) key2 = SENT;
  }

  const int first = __shfl(mysel, 0, 64);  // highest-energy candidate (or -1 if empty)
  if (lane < GS) {
    int idx = (mysel < 0) ? first : mysel;  // reference: -1 -> idx[:, :, :1]
    float4 o;
    if (idx >= 0) {
      float4 p = bp[idx];
      o.x = (p.x - cx) / RADIUS;
      o.y = (p.y - cy) / RADIUS;
      o.z = (p.z - cz) / RADIUS;
      o.w = p.w / RADIUS;
    } else {
      // masked_gather gives 0, then (0 - center)/radius
      o.x = (0.0f - cx) / RADIUS;
      o.y = (0.0f - cy) / RADIUS;
      o.z = (0.0f - cz) / RADIUS;
      o.w = 0.0f;
    }
    outg[(size_t)gid * GS + lane] = o;
  }
}

extern "C" void kernel_launch(void* const* d_in, const int* in_sizes, int n_in,
                              void* d_out, int out_size, void* d_ws, size_t ws_size,
                              hipStream_t stream) {
  const float4* pts = (const float4*)d_in[0];
  const int* lengths = (const int*)d_in[1];
  float* out = (float*)d_out;
  // out layout: groups (8,512,32,4) flat, then centers (8,512,3) flat
  float* centers = out + (size_t)B_ * NG * GS * 4;
  float4* groups = (float4*)out;

  fps_kernel<<<B_, TPB, 0, stream>>>(pts, lengths, centers);
  group_kernel<<<B_ * NG, 64, 0, stream>>>(pts, lengths, centers, groups);
}